// Round 9
// baseline (561.722 us; speedup 1.0000x reference)
//
#include <hip/hip_runtime.h>
#include <hip/hip_bf16.h>
#include <math.h>

#define B_ 16
#define T_ 4096
#define D_ 1024
#define U_ 1024
#define M_ (B_*T_)   // 65536

typedef __attribute__((ext_vector_type(8))) short short8;
typedef __attribute__((ext_vector_type(4))) short short4v;
typedef __attribute__((ext_vector_type(4))) float float4v;

static __device__ __forceinline__ short f2bf(float f) {
    unsigned u = __builtin_bit_cast(unsigned, f);
    u += 0x7FFFu + ((u >> 16) & 1u);   // RNE
    return (short)(u >> 16);
}
static __device__ __forceinline__ short bfc(float f) {
    __hip_bfloat16 b = __float2bfloat16(f);   // RNE, same bits as f2bf for finite inputs
    return (short)__builtin_bit_cast(unsigned short, b);
}
static __device__ __forceinline__ short8 cvt8(float4v lo, float4v hi) {
    short8 r;
    r[0]=bfc(lo[0]); r[1]=bfc(lo[1]); r[2]=bfc(lo[2]); r[3]=bfc(lo[3]);
    r[4]=bfc(hi[0]); r[5]=bfc(hi[1]); r[6]=bfc(hi[2]); r[7]=bfc(hi[3]);
    return r;
}
static __device__ __forceinline__ float fast_tanh(float x) {
    float c = fminf(fmaxf(2.f * x, -30.f), 30.f);
    float t = __expf(c);
    return __fdividef(t - 1.f, t + 1.f);
}

#define GLLDS(GP, LP) __builtin_amdgcn_global_load_lds( \
    (const __attribute__((address_space(1))) void*)(GP), \
    (__attribute__((address_space(3))) void*)(LP), 16, 0, 0)

// ---------------- kernel 1 (prep): hb partials + W2 transpose/convert. (verbatim R8)
__global__ void prep_fused(const float* __restrict__ h, const float* __restrict__ W1,
                           const float* __restrict__ b1, const float* __restrict__ b2,
                           const float* __restrict__ W2,
                           float* __restrict__ hbp, short* __restrict__ W2T) {
    int bx = blockIdx.x;
    if (bx < 256) {
        int kc = bx >> 6;
        int gid = (bx & 63) * 256 + threadIdx.x;
        int b = gid >> 10, u = gid & 1023;
        const float* hr = h + b * D_ + kc * 256;
        const float* w = W1 + (size_t)(kc * 256) * U_ + u;
        float s0 = 0.f, s1 = 0.f, s2 = 0.f, s3 = 0.f;
        for (int k = 0; k < 256; k += 4) {
            s0 += hr[k+0] * w[(size_t)(k+0) * U_];
            s1 += hr[k+1] * w[(size_t)(k+1) * U_];
            s2 += hr[k+2] * w[(size_t)(k+2) * U_];
            s3 += hr[k+3] * w[(size_t)(k+3) * U_];
        }
        float s = ((s0 + s1) + (s2 + s3));
        if (kc == 0) s += b1[u] + b2[u];
        hbp[kc * 16384 + gid] = s;
    } else {
        __shared__ short t[64][65];
        int x = bx - 256;
        int k0 = (x >> 4) * 64, u0 = (x & 15) * 64;
        int tx = threadIdx.x & 63, ty = threadIdx.x >> 6;
        #pragma unroll
        for (int r = 0; r < 16; ++r) {
            int kk = ty * 16 + r;
            t[kk][tx] = f2bf(W2[(size_t)(k0 + kk) * U_ + u0 + tx]);
        }
        __syncthreads();
        #pragma unroll
        for (int r = 0; r < 16; ++r) {
            int uu = ty * 16 + r;
            W2T[(size_t)(u0 + uu) * D_ + k0 + tx] = t[tx][uu];
        }
    }
}

// ---------------- kernel 2: 8-phase GEMM, A staged as F32 via global_load_lds
// (counted-vmcnt pipeline preserved; no VGPR landing), converted f32->bf16 AFTER
// ds_read. A single-buffered full tile (64KB f32): A-ph0 rows {0-63,128-191} die
// after ph0 -> restaged at ph1(t) for t+1; A-ph2 rows {64-127,192-255} die after
// ph2 -> restaged at ph3(t). B unchanged (bf16 GLLDS dbuf).
// Wait ledger (each wait immediately precedes a barrier -> cross-wave valid):
//   ph1-end vmcnt(6): A-ph2(t) younger set = B-hi(t+1) 2 + A-ph0(t+1) 4.
//   tile-end vmcnt(8): A-ph0(t+1)+B(t+1); younger = B-lo(t+2) 2 + A-ph2(t+1) 4 + B-hi(t+2) 2.
//   tails: ph1-end t=15 -> 0; tile-end t=14 -> 4, t=15 -> none. Prologue: 8.
// A swizzle at 32B granule: phys_u = u ^ (row&7); 2-way bank aliasing only (free).
__global__ __launch_bounds__(512, 2) void gemm_score_8ph(
    const float* __restrict__ encf,  // enc f32 [M_, D_]
    const short* __restrict__ W2T,   // bf16 [U_, D_]
    const float* __restrict__ hbp,   // [4][B_, U_]
    const float* __restrict__ V,
    float* __restrict__ scorepart)   // [4][M_]
{
    __shared__ __align__(16) short lds[65536];   // A f32: bytes [0,65536); B bf16: [65536,131072)

    const int tid = threadIdx.x;
    const int g = blockIdx.x;
    const int c = g & 7, q = g >> 3;            // XCD round-robin; 1024 % 8 == 0 -> bijective
    const int ntile = q & 3;
    const int mtile = (q >> 2) * 8 + c;
    const int row0 = mtile * 256, n0 = ntile * 256;
    const int bidx = row0 >> 12;

    const int lane = tid & 63;
    const int wv = tid >> 6;
    const int wm = wv >> 2, wn = wv & 3;        // 2M x 4N waves
    const int lm = lane & 15, quad = lane >> 4;

    // ---- A staging (f32): one GLLDS round = 512 thr x 16B = 8KB = 32 rows x 256B.
    // Source pre-swizzled at 32B granule: phys unit (tid&15)>>1 holds logical
    // unit ((tid&15)>>1)^(srow&7); (tid&1) picks the 16B half.
    const int srow32 = tid >> 4;                // 0..31
    const int scol = ((((tid & 15) >> 1) ^ (srow32 & 7)) << 3) + ((tid & 1) << 2);
    const float* aSrc = encf + (size_t)(row0 + srow32) * D_ + scol;
    char* aDst = (char*)lds + tid * 16;         // thread-linear dest

#define STG_A32(kt, R) do { \
    GLLDS(aSrc + (size_t)(R) * D_ + (kt) * 64,        aDst + (R) * 256); \
    GLLDS(aSrc + (size_t)((R) + 32) * D_ + (kt) * 64, aDst + (R) * 256 + 8192); \
} while (0)

    // ---- B staging (bf16, unchanged from verified kernel)
    const int srowB = tid >> 3;
    const int lslotB = (tid & 7) ^ (srowB & 7);
    const short* bS = W2T + (size_t)(n0 + srowB) * D_ + lslotB * 8;
    short* bD = lds + 32768 + tid * 8;
#define STG_B(kt, h, bf) do { \
    GLLDS(bS + (size_t)((h) * 128) * D_ + (kt) * 64,      bD + (bf) * 16384 + (h) * 8192); \
    GLLDS(bS + (size_t)((h) * 128 + 64) * D_ + (kt) * 64, bD + (bf) * 16384 + (h) * 8192 + 4096); \
} while (0)
#define LDS_RD(off) (*(const short8*)(lds + (off)))
#define MFMA(a, b, c) __builtin_amdgcn_mfma_f32_16x16x32_bf16((a), (b), (c), 0, 0, 0)
// read one A fragment pair (k=quad*8.. and k=quad*8+32..) at tile-row rw, cvt to bf16
#define LDA_FRAG(d0, d1, rw) do { \
    const int _r = (rw); \
    const int _p0 = _r * 256 + ((quad ^ (_r & 7)) << 5); \
    const int _p1 = _r * 256 + (((quad + 4) ^ (_r & 7)) << 5); \
    float4v _a = *(const float4v*)((const char*)lds + _p0); \
    float4v _b = *(const float4v*)((const char*)lds + _p0 + 16); \
    float4v _c = *(const float4v*)((const char*)lds + _p1); \
    float4v _d = *(const float4v*)((const char*)lds + _p1 + 16); \
    d0 = cvt8(_a, _b); d1 = cvt8(_c, _d); \
} while (0)

    // B read bases (shorts, within [32768, 65536))
    const int bB0 = 32768 + (wn * 64 + lm) * 64 + (quad ^ (lm & 7)) * 8;
    const int bB1 = bB0 ^ 32;

    float4v acc[8][4] = {};
    short8 Af[4][2], Bf[4][2];

    // ---- prologue: B(0), A-ph0(0), A-ph2(0), B(1).  vmcnt(8) waits A-ph0(0)+B(0).
    STG_B(0, 0, 0); STG_B(0, 1, 0);
    STG_A32(0, 0); STG_A32(0, 128);
    STG_A32(0, 64); STG_A32(0, 192);
    STG_B(1, 0, 1); STG_B(1, 1, 1);
    asm volatile("s_waitcnt vmcnt(8)" ::: "memory");
    __builtin_amdgcn_s_barrier();
    __builtin_amdgcn_sched_barrier(0);

    for (int t = 0; t < 16; ++t) {
        const int bufS = (t & 1) * 16384;
        // ---------- phase 0: A-ph0 frags (f32 reads + cvt) + B-lo frags; no staging
        #pragma unroll
        for (int mi = 0; mi < 4; ++mi)
            LDA_FRAG(Af[mi][0], Af[mi][1], wm * 128 + mi * 16 + lm);
        #pragma unroll
        for (int ni = 0; ni < 2; ++ni) {
            Bf[ni][0] = LDS_RD(bufS + bB0 + ni * 1024);
            Bf[ni][1] = LDS_RD(bufS + bB1 + ni * 1024);
        }
        __builtin_amdgcn_s_barrier();
        __builtin_amdgcn_s_setprio(1);
        #pragma unroll
        for (int mi = 0; mi < 4; ++mi)
            #pragma unroll
            for (int ni = 0; ni < 2; ++ni) {
                acc[mi][ni] = MFMA(Af[mi][0], Bf[ni][0], acc[mi][ni]);
                acc[mi][ni] = MFMA(Af[mi][1], Bf[ni][1], acc[mi][ni]);
            }
        __builtin_amdgcn_s_setprio(0);
        __builtin_amdgcn_s_barrier();
        // ---------- phase 1: B-hi frags; stage A-ph0(t+1) into rows {0-63,128-191}
        #pragma unroll
        for (int ni = 0; ni < 2; ++ni) {
            Bf[2 + ni][0] = LDS_RD(bufS + bB0 + (2 + ni) * 1024);
            Bf[2 + ni][1] = LDS_RD(bufS + bB1 + (2 + ni) * 1024);
        }
        if (t < 15) { STG_A32(t + 1, 0); STG_A32(t + 1, 128); }
        __builtin_amdgcn_s_barrier();
        __builtin_amdgcn_s_setprio(1);
        #pragma unroll
        for (int mi = 0; mi < 4; ++mi)
            #pragma unroll
            for (int ni = 0; ni < 2; ++ni) {
                acc[mi][2 + ni] = MFMA(Af[mi][0], Bf[2 + ni][0], acc[mi][2 + ni]);
                acc[mi][2 + ni] = MFMA(Af[mi][1], Bf[2 + ni][1], acc[mi][2 + ni]);
            }
        __builtin_amdgcn_s_setprio(0);
        if (t < 15) { asm volatile("s_waitcnt vmcnt(6)" ::: "memory"); }
        else        { asm volatile("s_waitcnt vmcnt(0)" ::: "memory"); }
        __builtin_amdgcn_s_barrier();           // A-ph2(t) now visible to all waves
        // ---------- phase 2: A-ph2 frags (rows +64); stage B-lo(t+2)
        #pragma unroll
        for (int mi = 0; mi < 4; ++mi)
            LDA_FRAG(Af[mi][0], Af[mi][1], wm * 128 + 64 + mi * 16 + lm);
        if (t < 14) STG_B(t + 2, 0, t & 1);
        __builtin_amdgcn_s_barrier();
        __builtin_amdgcn_s_setprio(1);
        #pragma unroll
        for (int mi = 0; mi < 4; ++mi)
            #pragma unroll
            for (int ni = 0; ni < 2; ++ni) {
                acc[4 + mi][ni] = MFMA(Af[mi][0], Bf[ni][0], acc[4 + mi][ni]);
                acc[4 + mi][ni] = MFMA(Af[mi][1], Bf[ni][1], acc[4 + mi][ni]);
            }
        __builtin_amdgcn_s_setprio(0);
        __builtin_amdgcn_s_barrier();
        // ---------- phase 3: stage A-ph2(t+1) rows {64-127,192-255} + B-hi(t+2)
        if (t < 15) { STG_A32(t + 1, 64); STG_A32(t + 1, 192); }
        if (t < 14) STG_B(t + 2, 1, t & 1);
        __builtin_amdgcn_s_barrier();
        __builtin_amdgcn_s_setprio(1);
        #pragma unroll
        for (int mi = 0; mi < 4; ++mi)
            #pragma unroll
            for (int ni = 0; ni < 2; ++ni) {
                acc[4 + mi][2 + ni] = MFMA(Af[mi][0], Bf[2 + ni][0], acc[4 + mi][2 + ni]);
                acc[4 + mi][2 + ni] = MFMA(Af[mi][1], Bf[2 + ni][1], acc[4 + mi][2 + ni]);
            }
        __builtin_amdgcn_s_setprio(0);
        if (t < 14)      { asm volatile("s_waitcnt vmcnt(8)" ::: "memory"); }
        else if (t == 14){ asm volatile("s_waitcnt vmcnt(4)" ::: "memory"); }
        __builtin_amdgcn_s_barrier();
        __builtin_amdgcn_sched_barrier(0);
    }

    // ---------- epilogue: score = sum_u tanh(acc + hb) * V (unchanged)
    float* sbuf = (float*)lds;
    float hbv[4], Vv[4];
    #pragma unroll
    for (int ni = 0; ni < 4; ++ni) {
        int U = n0 + wn * 64 + ni * 16 + lm;
        int o = bidx * U_ + U;
        hbv[ni] = hbp[o] + hbp[16384 + o] + hbp[32768 + o] + hbp[49152 + o];
        Vv[ni]  = V[U];
    }
    #pragma unroll
    for (int mi = 0; mi < 8; ++mi) {
        #pragma unroll
        for (int r = 0; r < 4; ++r) {
            float s = 0.f;
            #pragma unroll
            for (int ni = 0; ni < 4; ++ni)
                s += fast_tanh(acc[mi][ni][r] + hbv[ni]) * Vv[ni];
            #pragma unroll
            for (int off = 1; off < 16; off <<= 1)
                s += __shfl_xor(s, off, 64);
            if (lm == 0)
                sbuf[wn * 256 + wm * 128 + mi * 16 + quad * 4 + r] = s;
        }
    }
    __syncthreads();
    if (tid < 256)
        scorepart[(size_t)ntile * M_ + row0 + tid] =
            sbuf[tid] + sbuf[256 + tid] + sbuf[512 + tid] + sbuf[768 + tid];
}

// ---------------- kernel 3: fused softmax + context partials; enc f32 (verbatim R8).
__global__ __launch_bounds__(256) void ctx_softmax(
        const float* __restrict__ scorepart,
        const float* __restrict__ bv,
        const float* __restrict__ enc,
        float* __restrict__ out_attn,
        float* __restrict__ part)    // [512][1024] (in dead W2T region)
{
    __shared__ float sm[T_];
    __shared__ float wsm[128];
    __shared__ float lacc[1024];
    __shared__ float red[8];
    const int x = blockIdx.x, tid = threadIdx.x;
    const int b = x & 15, tc = x >> 4;
    const int wvi = tid >> 6;
    const float bv0 = bv[0];
    float lmax = -1e30f;
    #pragma unroll
    for (int i = 0; i < 16; ++i) {
        int t = tid + i * 256;
        const float* sp = scorepart + (size_t)b * T_ + t;
        float s = bv0 + sp[0] + sp[M_] + sp[2 * (size_t)M_] + sp[3 * (size_t)M_];
        sm[t] = s;
        lmax = fmaxf(lmax, s);
    }
    #pragma unroll
    for (int off = 1; off < 64; off <<= 1) lmax = fmaxf(lmax, __shfl_xor(lmax, off, 64));
    if ((tid & 63) == 0) red[wvi] = lmax;
    __syncthreads();
    const float m = fmaxf(fmaxf(red[0], red[1]), fmaxf(red[2], red[3]));
    float lsum = 0.f;
    #pragma unroll
    for (int i = 0; i < 16; ++i) lsum += __expf(sm[tid + i * 256] - m);
    #pragma unroll
    for (int off = 1; off < 64; off <<= 1) lsum += __shfl_xor(lsum, off, 64);
    if ((tid & 63) == 0) red[4 + wvi] = lsum;
    __syncthreads();
    const float tot = (red[4] + red[5]) + (red[6] + red[7]);
    const float rinv = 1.f / tot;
    if ((tid >> 7) == (tc & 1)) {
        int j = tid & 127;
        int t = tc * 128 + j;
        float w = __expf(sm[t] - m) * rinv;
        wsm[j] = w;
        out_attn[b * T_ + t] = w;
    }
    __syncthreads();
    const int par = tid >> 7;
    const int d0 = (tid & 127) * 8;
    const float* e0 = enc + (size_t)(b * T_ + tc * 128 + par) * D_ + d0;
    float4v a0 = {}, a1 = {};
    #pragma unroll 4
    for (int it = 0; it < 64; ++it) {
        float4v v0 = *(const float4v*)(e0 + (size_t)it * 2 * D_);
        float4v v1 = *(const float4v*)(e0 + (size_t)it * 2 * D_ + 4);
        float w = wsm[it * 2 + par];
        a0[0] += w * v0[0]; a0[1] += w * v0[1];
        a0[2] += w * v0[2]; a0[3] += w * v0[3];
        a1[0] += w * v1[0]; a1[1] += w * v1[1];
        a1[2] += w * v1[2]; a1[3] += w * v1[3];
    }
    if (par) {
        *(float4v*)(lacc + (tid & 127) * 8)     = a0;
        *(float4v*)(lacc + (tid & 127) * 8 + 4) = a1;
    }
    __syncthreads();
    if (!par) {
        const float* l = lacc + tid * 8;
        a0[0] += l[0]; a0[1] += l[1]; a0[2] += l[2]; a0[3] += l[3];
        a1[0] += l[4]; a1[1] += l[5]; a1[2] += l[6]; a1[3] += l[7];
        float4v* pp = (float4v*)(part + (size_t)x * 1024 + tid * 8);
        pp[0] = a0; pp[1] = a1;
    }
}

// ---------------- kernel 4: reduce context partials (verbatim)
__global__ void ctx_reduce_kernel(const float* __restrict__ part, float* __restrict__ ctx) {
    int gid = blockIdx.x * 256 + threadIdx.x;
    int b = gid >> 10, d = gid & 1023;
    float s = 0.f;
    #pragma unroll
    for (int tc = 0; tc < 32; ++tc) s += part[(size_t)(tc * 16 + b) * 1024 + d];
    ctx[gid] = s;
}

extern "C" void kernel_launch(void* const* d_in, const int* in_sizes, int n_in,
                              void* d_out, int out_size, void* d_ws, size_t ws_size,
                              hipStream_t stream) {
    const float* h   = (const float*)d_in[0];
    const float* enc = (const float*)d_in[1];
    const float* W1  = (const float*)d_in[2];
    const float* b1  = (const float*)d_in[3];
    const float* W2  = (const float*)d_in[4];
    const float* b2  = (const float*)d_in[5];
    const float* V   = (const float*)d_in[6];
    const float* bv  = (const float*)d_in[7];
    float* out = (float*)d_out;                 // [0,16384) context, [16384,81920) attn
    float* ws  = (float*)d_ws;

    float* hbp       = ws;                      // 256 KB
    float* scorepart = ws + 65536;              // 1 MB used of 2 MB slot
    short* W2T   = (short*)(ws + 65536 + 524288);          // 2 MB
    float* ctxpart   = (float*)W2T;             // ALIAS: W2T dead after gemm

    prep_fused<<<512, 256, 0, stream>>>(h, W1, b1, b2, W2, hbp, W2T);
    gemm_score_8ph<<<1024, 512, 0, stream>>>(enc, W2T, hbp, V, scorepart);
    ctx_softmax<<<512, 256, 0, stream>>>(scorepart, bv, enc, out + 16384, ctxpart);
    ctx_reduce_kernel<<<64, 256, 0, stream>>>(ctxpart, out);
}

// Round 10
// 547.549 us; speedup vs baseline: 1.0259x; 1.0259x over previous
//
#include <hip/hip_runtime.h>
#include <hip/hip_bf16.h>
#include <math.h>

#define B_ 16
#define T_ 4096
#define D_ 1024
#define U_ 1024
#define M_ (B_*T_)   // 65536

typedef __attribute__((ext_vector_type(8))) short short8;
typedef __attribute__((ext_vector_type(4))) short short4v;
typedef __attribute__((ext_vector_type(4))) float float4v;

static __device__ __forceinline__ short f2bf(float f) {
    unsigned u = __builtin_bit_cast(unsigned, f);
    u += 0x7FFFu + ((u >> 16) & 1u);   // RNE
    return (short)(u >> 16);
}
static __device__ __forceinline__ short bfc(float f) {
    __hip_bfloat16 b = __float2bfloat16(f);   // RNE, same bits as f2bf for finite inputs
    return (short)__builtin_bit_cast(unsigned short, b);
}
static __device__ __forceinline__ short8 cvt8(float4v lo, float4v hi) {
    short8 r;
    r[0]=bfc(lo[0]); r[1]=bfc(lo[1]); r[2]=bfc(lo[2]); r[3]=bfc(lo[3]);
    r[4]=bfc(hi[0]); r[5]=bfc(hi[1]); r[6]=bfc(hi[2]); r[7]=bfc(hi[3]);
    return r;
}
static __device__ __forceinline__ float fast_tanh(float x) {
    float c = fminf(fmaxf(2.f * x, -30.f), 30.f);
    float t = __expf(c);
    return __fdividef(t - 1.f, t + 1.f);
}

#define GLLDS(GP, LP) __builtin_amdgcn_global_load_lds( \
    (const __attribute__((address_space(1))) void*)(GP), \
    (__attribute__((address_space(3))) void*)(LP), 16, 0, 0)

// ---------------- kernel 1 (prep): hb partials + W2 transpose/convert. (verbatim)
__global__ void prep_fused(const float* __restrict__ h, const float* __restrict__ W1,
                           const float* __restrict__ b1, const float* __restrict__ b2,
                           const float* __restrict__ W2,
                           float* __restrict__ hbp, short* __restrict__ W2T) {
    int bx = blockIdx.x;
    if (bx < 256) {
        int kc = bx >> 6;
        int gid = (bx & 63) * 256 + threadIdx.x;
        int b = gid >> 10, u = gid & 1023;
        const float* hr = h + b * D_ + kc * 256;
        const float* w = W1 + (size_t)(kc * 256) * U_ + u;
        float s0 = 0.f, s1 = 0.f, s2 = 0.f, s3 = 0.f;
        for (int k = 0; k < 256; k += 4) {
            s0 += hr[k+0] * w[(size_t)(k+0) * U_];
            s1 += hr[k+1] * w[(size_t)(k+1) * U_];
            s2 += hr[k+2] * w[(size_t)(k+2) * U_];
            s3 += hr[k+3] * w[(size_t)(k+3) * U_];
        }
        float s = ((s0 + s1) + (s2 + s3));
        if (kc == 0) s += b1[u] + b2[u];
        hbp[kc * 16384 + gid] = s;
    } else {
        __shared__ short t[64][65];
        int x = bx - 256;
        int k0 = (x >> 4) * 64, u0 = (x & 15) * 64;
        int tx = threadIdx.x & 63, ty = threadIdx.x >> 6;
        #pragma unroll
        for (int r = 0; r < 16; ++r) {
            int kk = ty * 16 + r;
            t[kk][tx] = f2bf(W2[(size_t)(k0 + kk) * U_ + u0 + tx]);
        }
        __syncthreads();
        #pragma unroll
        for (int r = 0; r < 16; ++r) {
            int uu = ty * 16 + r;
            W2T[(size_t)(u0 + uu) * D_ + k0 + tx] = t[tx][uu];
        }
    }
}

// ---------------- kernel 2: 8-phase GEMM, A staged as F32 via global_load_lds,
// converted f32->bf16 AFTER ds_read. Identical to round-9 EXCEPT the A swizzle is
// now 16B-granule with key (row & 15):
//   LDS[row][p] holds logical 16B-unit p ^ (row&15).
//   Stage: thread t -> phys unit (t&15), source unit (t&15)^(srow32&15); valid for
//   both halves since every staged row == srow32 (mod 16) (R in {0,64,128,192}, +32).
//   Read: phys = lu ^ (r&15), lu in {2q, 2q+1, 2q+8, 2q+9}; with r&15 == lm each
//   quarter-wave is a PERFECT permutation of the 16 units -> 0 bank conflicts
//   (verified against the known-good bf16 pattern's bank math).
// Wait ledger unchanged from round 9 (only address bits changed, not issue order).
__global__ __launch_bounds__(512, 2) void gemm_score_8ph(
    const float* __restrict__ encf,  // enc f32 [M_, D_]
    const short* __restrict__ W2T,   // bf16 [U_, D_]
    const float* __restrict__ hbp,   // [4][B_, U_]
    const float* __restrict__ V,
    float* __restrict__ scorepart)   // [4][M_]
{
    __shared__ __align__(16) short lds[65536];   // A f32: bytes [0,65536); B bf16: [65536,131072)

    const int tid = threadIdx.x;
    const int g = blockIdx.x;
    const int c = g & 7, q = g >> 3;            // XCD round-robin; 1024 % 8 == 0 -> bijective
    const int ntile = q & 3;
    const int mtile = (q >> 2) * 8 + c;
    const int row0 = mtile * 256, n0 = ntile * 256;
    const int bidx = row0 >> 12;

    const int lane = tid & 63;
    const int wv = tid >> 6;
    const int wm = wv >> 2, wn = wv & 3;        // 2M x 4N waves
    const int lm = lane & 15, quad = lane >> 4;

    // ---- A staging (f32): one GLLDS round = 512 thr x 16B = 8KB = 32 rows x 256B.
    // 16B-granule pre-swizzled source: logical unit = (tid&15) ^ (srow32&15).
    const int srow32 = tid >> 4;                // 0..31
    const int scol = (((tid & 15) ^ (srow32 & 15)) << 2);   // float offset
    const float* aSrc = encf + (size_t)(row0 + srow32) * D_ + scol;
    char* aDst = (char*)lds + tid * 16;         // thread-linear dest

#define STG_A32(kt, R) do { \
    GLLDS(aSrc + (size_t)(R) * D_ + (kt) * 64,        aDst + (R) * 256); \
    GLLDS(aSrc + (size_t)((R) + 32) * D_ + (kt) * 64, aDst + (R) * 256 + 8192); \
} while (0)

    // ---- B staging (bf16, unchanged from verified kernel)
    const int srowB = tid >> 3;
    const int lslotB = (tid & 7) ^ (srowB & 7);
    const short* bS = W2T + (size_t)(n0 + srowB) * D_ + lslotB * 8;
    short* bD = lds + 32768 + tid * 8;
#define STG_B(kt, h, bf) do { \
    GLLDS(bS + (size_t)((h) * 128) * D_ + (kt) * 64,      bD + (bf) * 16384 + (h) * 8192); \
    GLLDS(bS + (size_t)((h) * 128 + 64) * D_ + (kt) * 64, bD + (bf) * 16384 + (h) * 8192 + 4096); \
} while (0)
#define LDS_RD(off) (*(const short8*)(lds + (off)))
#define MFMA(a, b, c) __builtin_amdgcn_mfma_f32_16x16x32_bf16((a), (b), (c), 0, 0, 0)
// read one A fragment pair (k=quad*8 and k=quad*8+32) at tile-row rw, cvt to bf16.
// 16B units: {2q, 2q+1} and {2q+8, 2q+9}, each XOR'd with (rw & 15).
#define LDA_FRAG(d0, d1, rw) do { \
    const int _r = (rw); \
    const int _k = _r & 15; \
    const char* _base = (const char*)lds + _r * 256; \
    float4v _a = *(const float4v*)(_base + ((((2 * quad)     ^ _k) ) << 4)); \
    float4v _b = *(const float4v*)(_base + ((((2 * quad + 1) ^ _k) ) << 4)); \
    float4v _c = *(const float4v*)(_base + ((((2 * quad + 8) ^ _k) ) << 4)); \
    float4v _d = *(const float4v*)(_base + ((((2 * quad + 9) ^ _k) ) << 4)); \
    d0 = cvt8(_a, _b); d1 = cvt8(_c, _d); \
} while (0)

    // B read bases (shorts, within [32768, 65536))
    const int bB0 = 32768 + (wn * 64 + lm) * 64 + (quad ^ (lm & 7)) * 8;
    const int bB1 = bB0 ^ 32;

    float4v acc[8][4] = {};
    short8 Af[4][2], Bf[4][2];

    // ---- prologue: B(0), A-ph0(0), A-ph2(0), B(1).  vmcnt(8) waits A-ph0(0)+B(0).
    STG_B(0, 0, 0); STG_B(0, 1, 0);
    STG_A32(0, 0); STG_A32(0, 128);
    STG_A32(0, 64); STG_A32(0, 192);
    STG_B(1, 0, 1); STG_B(1, 1, 1);
    asm volatile("s_waitcnt vmcnt(8)" ::: "memory");
    __builtin_amdgcn_s_barrier();
    __builtin_amdgcn_sched_barrier(0);

    for (int t = 0; t < 16; ++t) {
        const int bufS = (t & 1) * 16384;
        // ---------- phase 0: A-ph0 frags (f32 reads + cvt) + B-lo frags; no staging
        #pragma unroll
        for (int mi = 0; mi < 4; ++mi)
            LDA_FRAG(Af[mi][0], Af[mi][1], wm * 128 + mi * 16 + lm);
        #pragma unroll
        for (int ni = 0; ni < 2; ++ni) {
            Bf[ni][0] = LDS_RD(bufS + bB0 + ni * 1024);
            Bf[ni][1] = LDS_RD(bufS + bB1 + ni * 1024);
        }
        __builtin_amdgcn_s_barrier();
        __builtin_amdgcn_s_setprio(1);
        #pragma unroll
        for (int mi = 0; mi < 4; ++mi)
            #pragma unroll
            for (int ni = 0; ni < 2; ++ni) {
                acc[mi][ni] = MFMA(Af[mi][0], Bf[ni][0], acc[mi][ni]);
                acc[mi][ni] = MFMA(Af[mi][1], Bf[ni][1], acc[mi][ni]);
            }
        __builtin_amdgcn_s_setprio(0);
        __builtin_amdgcn_s_barrier();
        // ---------- phase 1: B-hi frags; stage A-ph0(t+1) into rows {0-63,128-191}
        #pragma unroll
        for (int ni = 0; ni < 2; ++ni) {
            Bf[2 + ni][0] = LDS_RD(bufS + bB0 + (2 + ni) * 1024);
            Bf[2 + ni][1] = LDS_RD(bufS + bB1 + (2 + ni) * 1024);
        }
        if (t < 15) { STG_A32(t + 1, 0); STG_A32(t + 1, 128); }
        __builtin_amdgcn_s_barrier();
        __builtin_amdgcn_s_setprio(1);
        #pragma unroll
        for (int mi = 0; mi < 4; ++mi)
            #pragma unroll
            for (int ni = 0; ni < 2; ++ni) {
                acc[mi][2 + ni] = MFMA(Af[mi][0], Bf[2 + ni][0], acc[mi][2 + ni]);
                acc[mi][2 + ni] = MFMA(Af[mi][1], Bf[2 + ni][1], acc[mi][2 + ni]);
            }
        __builtin_amdgcn_s_setprio(0);
        if (t < 15) { asm volatile("s_waitcnt vmcnt(6)" ::: "memory"); }
        else        { asm volatile("s_waitcnt vmcnt(0)" ::: "memory"); }
        __builtin_amdgcn_s_barrier();           // A-ph2(t) now visible to all waves
        // ---------- phase 2: A-ph2 frags (rows +64); stage B-lo(t+2)
        #pragma unroll
        for (int mi = 0; mi < 4; ++mi)
            LDA_FRAG(Af[mi][0], Af[mi][1], wm * 128 + 64 + mi * 16 + lm);
        if (t < 14) STG_B(t + 2, 0, t & 1);
        __builtin_amdgcn_s_barrier();
        __builtin_amdgcn_s_setprio(1);
        #pragma unroll
        for (int mi = 0; mi < 4; ++mi)
            #pragma unroll
            for (int ni = 0; ni < 2; ++ni) {
                acc[4 + mi][ni] = MFMA(Af[mi][0], Bf[ni][0], acc[4 + mi][ni]);
                acc[4 + mi][ni] = MFMA(Af[mi][1], Bf[ni][1], acc[4 + mi][ni]);
            }
        __builtin_amdgcn_s_setprio(0);
        __builtin_amdgcn_s_barrier();
        // ---------- phase 3: stage A-ph2(t+1) rows {64-127,192-255} + B-hi(t+2)
        if (t < 15) { STG_A32(t + 1, 64); STG_A32(t + 1, 192); }
        if (t < 14) STG_B(t + 2, 1, t & 1);
        __builtin_amdgcn_s_barrier();
        __builtin_amdgcn_s_setprio(1);
        #pragma unroll
        for (int mi = 0; mi < 4; ++mi)
            #pragma unroll
            for (int ni = 0; ni < 2; ++ni) {
                acc[4 + mi][2 + ni] = MFMA(Af[mi][0], Bf[2 + ni][0], acc[4 + mi][2 + ni]);
                acc[4 + mi][2 + ni] = MFMA(Af[mi][1], Bf[2 + ni][1], acc[4 + mi][2 + ni]);
            }
        __builtin_amdgcn_s_setprio(0);
        if (t < 14)      { asm volatile("s_waitcnt vmcnt(8)" ::: "memory"); }
        else if (t == 14){ asm volatile("s_waitcnt vmcnt(4)" ::: "memory"); }
        __builtin_amdgcn_s_barrier();
        __builtin_amdgcn_sched_barrier(0);
    }

    // ---------- epilogue: score = sum_u tanh(acc + hb) * V (unchanged)
    float* sbuf = (float*)lds;
    float hbv[4], Vv[4];
    #pragma unroll
    for (int ni = 0; ni < 4; ++ni) {
        int U = n0 + wn * 64 + ni * 16 + lm;
        int o = bidx * U_ + U;
        hbv[ni] = hbp[o] + hbp[16384 + o] + hbp[32768 + o] + hbp[49152 + o];
        Vv[ni]  = V[U];
    }
    #pragma unroll
    for (int mi = 0; mi < 8; ++mi) {
        #pragma unroll
        for (int r = 0; r < 4; ++r) {
            float s = 0.f;
            #pragma unroll
            for (int ni = 0; ni < 4; ++ni)
                s += fast_tanh(acc[mi][ni][r] + hbv[ni]) * Vv[ni];
            #pragma unroll
            for (int off = 1; off < 16; off <<= 1)
                s += __shfl_xor(s, off, 64);
            if (lm == 0)
                sbuf[wn * 256 + wm * 128 + mi * 16 + quad * 4 + r] = s;
        }
    }
    __syncthreads();
    if (tid < 256)
        scorepart[(size_t)ntile * M_ + row0 + tid] =
            sbuf[tid] + sbuf[256 + tid] + sbuf[512 + tid] + sbuf[768 + tid];
}

// ---------------- kernel 3: fused softmax + context partials; enc f32 (verbatim).
__global__ __launch_bounds__(256) void ctx_softmax(
        const float* __restrict__ scorepart,
        const float* __restrict__ bv,
        const float* __restrict__ enc,
        float* __restrict__ out_attn,
        float* __restrict__ part)    // [512][1024] (in dead W2T region)
{
    __shared__ float sm[T_];
    __shared__ float wsm[128];
    __shared__ float lacc[1024];
    __shared__ float red[8];
    const int x = blockIdx.x, tid = threadIdx.x;
    const int b = x & 15, tc = x >> 4;
    const int wvi = tid >> 6;
    const float bv0 = bv[0];
    float lmax = -1e30f;
    #pragma unroll
    for (int i = 0; i < 16; ++i) {
        int t = tid + i * 256;
        const float* sp = scorepart + (size_t)b * T_ + t;
        float s = bv0 + sp[0] + sp[M_] + sp[2 * (size_t)M_] + sp[3 * (size_t)M_];
        sm[t] = s;
        lmax = fmaxf(lmax, s);
    }
    #pragma unroll
    for (int off = 1; off < 64; off <<= 1) lmax = fmaxf(lmax, __shfl_xor(lmax, off, 64));
    if ((tid & 63) == 0) red[wvi] = lmax;
    __syncthreads();
    const float m = fmaxf(fmaxf(red[0], red[1]), fmaxf(red[2], red[3]));
    float lsum = 0.f;
    #pragma unroll
    for (int i = 0; i < 16; ++i) lsum += __expf(sm[tid + i * 256] - m);
    #pragma unroll
    for (int off = 1; off < 64; off <<= 1) lsum += __shfl_xor(lsum, off, 64);
    if ((tid & 63) == 0) red[4 + wvi] = lsum;
    __syncthreads();
    const float tot = (red[4] + red[5]) + (red[6] + red[7]);
    const float rinv = 1.f / tot;
    if ((tid >> 7) == (tc & 1)) {
        int j = tid & 127;
        int t = tc * 128 + j;
        float w = __expf(sm[t] - m) * rinv;
        wsm[j] = w;
        out_attn[b * T_ + t] = w;
    }
    __syncthreads();
    const int par = tid >> 7;
    const int d0 = (tid & 127) * 8;
    const float* e0 = enc + (size_t)(b * T_ + tc * 128 + par) * D_ + d0;
    float4v a0 = {}, a1 = {};
    #pragma unroll 4
    for (int it = 0; it < 64; ++it) {
        float4v v0 = *(const float4v*)(e0 + (size_t)it * 2 * D_);
        float4v v1 = *(const float4v*)(e0 + (size_t)it * 2 * D_ + 4);
        float w = wsm[it * 2 + par];
        a0[0] += w * v0[0]; a0[1] += w * v0[1];
        a0[2] += w * v0[2]; a0[3] += w * v0[3];
        a1[0] += w * v1[0]; a1[1] += w * v1[1];
        a1[2] += w * v1[2]; a1[3] += w * v1[3];
    }
    if (par) {
        *(float4v*)(lacc + (tid & 127) * 8)     = a0;
        *(float4v*)(lacc + (tid & 127) * 8 + 4) = a1;
    }
    __syncthreads();
    if (!par) {
        const float* l = lacc + tid * 8;
        a0[0] += l[0]; a0[1] += l[1]; a0[2] += l[2]; a0[3] += l[3];
        a1[0] += l[4]; a1[1] += l[5]; a1[2] += l[6]; a1[3] += l[7];
        float4v* pp = (float4v*)(part + (size_t)x * 1024 + tid * 8);
        pp[0] = a0; pp[1] = a1;
    }
}

// ---------------- kernel 4: reduce context partials (verbatim)
__global__ void ctx_reduce_kernel(const float* __restrict__ part, float* __restrict__ ctx) {
    int gid = blockIdx.x * 256 + threadIdx.x;
    int b = gid >> 10, d = gid & 1023;
    float s = 0.f;
    #pragma unroll
    for (int tc = 0; tc < 32; ++tc) s += part[(size_t)(tc * 16 + b) * 1024 + d];
    ctx[gid] = s;
}

extern "C" void kernel_launch(void* const* d_in, const int* in_sizes, int n_in,
                              void* d_out, int out_size, void* d_ws, size_t ws_size,
                              hipStream_t stream) {
    const float* h   = (const float*)d_in[0];
    const float* enc = (const float*)d_in[1];
    const float* W1  = (const float*)d_in[2];
    const float* b1  = (const float*)d_in[3];
    const float* W2  = (const float*)d_in[4];
    const float* b2  = (const float*)d_in[5];
    const float* V   = (const float*)d_in[6];
    const float* bv  = (const float*)d_in[7];
    float* out = (float*)d_out;                 // [0,16384) context, [16384,81920) attn
    float* ws  = (float*)d_ws;

    float* hbp       = ws;                      // 256 KB
    float* scorepart = ws + 65536;              // 1 MB used of 2 MB slot
    short* W2T   = (short*)(ws + 65536 + 524288);          // 2 MB
    float* ctxpart   = (float*)W2T;             // ALIAS: W2T dead after gemm

    prep_fused<<<512, 256, 0, stream>>>(h, W1, b1, b2, W2, hbp, W2T);
    gemm_score_8ph<<<1024, 512, 0, stream>>>(enc, W2T, hbp, V, scorepart);
    ctx_softmax<<<512, 256, 0, stream>>>(scorepart, bv, enc, out + 16384, ctxpart);
    ctx_reduce_kernel<<<64, 256, 0, stream>>>(ctxpart, out);
}